// Round 2
// baseline (263.737 us; speedup 1.0000x reference)
//
#include <hip/hip_runtime.h>

// B=32, H=W=128, C_IN=C_OUT=32, 3x3 SAME conv, per-sample hypernet weights
// Wk[b] = (P[b] @ dense_w).reshape(3,3,32,32).
//
// Implicit GEMM per image: Y[p,co] = sum_k Xpatch[p,k]*W[k,co]; M=16384,N=32,K=288.
// K-chunk kc (32 wide) == tap (kh,kw)=(kc/3,kc%3), chunk-local k == ci.
// 16x16x32 f16 MFMA, A-frag A[m=lane&15][k=(lane>>4)*8+j] = 8 consecutive ci of
// one pixel = two float4 loads from X.

#define BATCH 32
#define HDIM 128
#define WDIM 128
#define CIN 32
#define COUT 32
#define PDIM 128
#define KCOLS 9216  // 3*3*32*32

typedef _Float16 f16x8 __attribute__((ext_vector_type(8)));
typedef float f32x4 __attribute__((ext_vector_type(4)));

// ---------------------------------------------------------------------------
// Kernel A: A = P @ dense_w (32x128 @ 128x9216) -> f16, swizzled to MFMA
// B-fragment layout: WB[b][kc][ct][lane][j8], lane=(ci>>3)*16+(co&15),
// j8=ci&7, ct=co>>4. 288 blocks: blk = layer*144 + colgroup; thread = 1 col
// x 4 batches; P rows for this layer staged in LDS (wave-uniform broadcast).
// ---------------------------------------------------------------------------
__global__ __launch_bounds__(256) void hyper_gemm(const float* __restrict__ P,
                                                  const float* __restrict__ Dw,
                                                  unsigned short* __restrict__ WB) {
    __shared__ float Pl[16 * PDIM];  // 16 batches x 128 = 8 KB
    const int tid = threadIdx.x;
    const int layer = blockIdx.x / 144;  // 0..1 -> batches [layer*16, layer*16+16)
    const int cg = blockIdx.x % 144;     // 64-column group

#pragma unroll
    for (int i = 0; i < 8; ++i) {
        int idx = i * 256 + tid;  // 0..2047
        Pl[idx] = P[layer * 16 * PDIM + idx];
    }
    __syncthreads();

    const int c = tid & 63;
    const int bg = tid >> 6;  // 0..3 -> 4 batches each
    const int col = cg * 64 + c;
    const int brow = bg * 4;

    float acc[4] = {0.f, 0.f, 0.f, 0.f};
#pragma unroll 8
    for (int m = 0; m < PDIM; ++m) {
        float dw = Dw[m * KCOLS + col];  // coalesced across the 64-lane wave
#pragma unroll
        for (int j = 0; j < 4; ++j) acc[j] += dw * Pl[(brow + j) * PDIM + m];
    }

    // col = ((tap)*32 + ci)*32 + co
    const int k = col >> 5;
    const int co = col & 31;
    const int kc = k >> 5;  // tap 0..8
    const int ci = k & 31;
    const int base = ((kc * 2 + (co >> 4)) * 64 + (ci >> 3) * 16 + (co & 15)) * 8 + (ci & 7);
    const int b0 = layer * 16 + brow;
#pragma unroll
    for (int j = 0; j < 4; ++j) {
        _Float16 v = (_Float16)acc[j];
        WB[(size_t)(b0 + j) * KCOLS + base] = __builtin_bit_cast(unsigned short, v);
    }
}

// ---------------------------------------------------------------------------
// Kernel B: implicit-GEMM conv. Grid 2048 = 32 b x 64 half-row-groups,
// 256 thr = 4 waves, wave = one half-row (4 tiles of 16 px).
// Per-image fragment table (18 KB) staged once in LDS; B-frags ds_read per
// tile (launch_bounds forces <=64 VGPR so 8 waves/SIMD -> 32 waves/CU).
// ---------------------------------------------------------------------------
__global__ __launch_bounds__(256, 8) void cond_conv(const float* __restrict__ X,
                                                    const unsigned short* __restrict__ WB,
                                                    float* __restrict__ Y) {
    __shared__ unsigned short WBl[KCOLS];  // 18432 B
    const int tid = threadIdx.x;
    const int b = blockIdx.x >> 6;
    const int hhg = blockIdx.x & 63;

    // stage the whole per-image fragment table (16B chunks, coalesced)
    {
        const uint4* src = (const uint4*)(WB + (size_t)b * KCOLS);
        uint4* dst = (uint4*)WBl;
        for (int i = tid; i < KCOLS / 8; i += 256) dst[i] = src[i];
    }
    __syncthreads();

    const int wave = tid >> 6;
    const int lane = tid & 63;
    const int hr = hhg * 4 + wave;  // half-row 0..255
    const int h = hr >> 1;
    const int wbase = (hr & 1) * 64;
    const int quad = lane >> 4;
    const int m16 = lane & 15;

    const f32x4* X4 = (const f32x4*)X;

    for (int t = 0; t < 4; ++t) {
        const int w0 = wbase + t * 16;
        f32x4 acc0 = {0.f, 0.f, 0.f, 0.f};
        f32x4 acc1 = {0.f, 0.f, 0.f, 0.f};
#pragma unroll
        for (int kc = 0; kc < 9; ++kc) {
            const int kh = kc / 3, kw = kc % 3;
            const int hh = h + kh - 1;         // wave-uniform
            const int ww = w0 + m16 + kw - 1;  // per-lane
            const bool ok = (hh >= 0) & (hh < HDIM) & (ww >= 0) & (ww < WDIM);
            int idx = ((b * HDIM + hh) * WDIM + ww) * 8 + quad * 2;  // float4 units
            idx = ok ? idx : 0;
            f32x4 lo = X4[idx];
            f32x4 hi = X4[idx + 1];
            if (!ok) { lo = (f32x4)(0.f); hi = (f32x4)(0.f); }
            f16x8 a;
#pragma unroll
            for (int j = 0; j < 4; ++j) {
                a[j] = (_Float16)lo[j];
                a[4 + j] = (_Float16)hi[j];
            }
            const f16x8 bf0 = *(const f16x8*)(WBl + ((kc * 2 + 0) * 64 + lane) * 8);
            const f16x8 bf1 = *(const f16x8*)(WBl + ((kc * 2 + 1) * 64 + lane) * 8);
            acc0 = __builtin_amdgcn_mfma_f32_16x16x32_f16(a, bf0, acc0, 0, 0, 0);
            acc1 = __builtin_amdgcn_mfma_f32_16x16x32_f16(a, bf1, acc1, 0, 0, 0);
        }
        // D layout: col = lane&15 (co), row = quad*4 + r (pixel)
        float* yp = Y + (((size_t)(b * HDIM + h) * WDIM) + w0 + quad * 4) * COUT + m16;
#pragma unroll
        for (int r = 0; r < 4; ++r) {
            yp[r * COUT] = acc0[r];
            yp[r * COUT + 16] = acc1[r];
        }
    }
}

extern "C" void kernel_launch(void* const* d_in, const int* in_sizes, int n_in,
                              void* d_out, int out_size, void* d_ws, size_t ws_size,
                              hipStream_t stream) {
    const float* X = (const float*)d_in[0];   // [32,128,128,32]
    const float* P = (const float*)d_in[1];   // [32,128]
    const float* Dw = (const float*)d_in[2];  // [128,9216]
    float* Y = (float*)d_out;                 // [32,128,128,32]
    unsigned short* WB = (unsigned short*)d_ws;  // 32*9216 f16 = 576 KiB

    hipLaunchKernelGGL(hyper_gemm, dim3(288), dim3(256), 0, stream, P, Dw, WB);
    hipLaunchKernelGGL(cond_conv, dim3(BATCH * 64), dim3(256), 0, stream, X, WB, Y);
}